// Round 2
// baseline (454.561 us; speedup 1.0000x reference)
//
#include <hip/hip_runtime.h>
#include <hip/hip_bf16.h>

#define LEN   16384
#define CIN   256
#define COUT  256
#define NB    8
#define NTAP  9
#define DIL   6
#define PADW  24
#define NSTEP 72                    // 9 taps * (256/32) channel chunks
#define PADROWS (LEN + 2*PADW)      // 16432

typedef __bf16 bf16x8 __attribute__((ext_vector_type(8)));
typedef float  f32x4  __attribute__((ext_vector_type(4)));
typedef unsigned short u16;
typedef u16 u16x8 __attribute__((ext_vector_type(8)));

// ---------------- ws layout ----------------
#define WKT_BYTES  (NB*NTAP*LEN*4)             // 4,718,592
#define WB_BYTES   (NSTEP*256*32*2)            // 1,179,648
#define XT_OFF     (WKT_BYTES + WB_BYTES)
#define XT_BYTES   ((size_t)NB*PADROWS*256*2)  // 67,305,472
#define SUMS_OFF   (XT_OFF + XT_BYTES)
#define SCB_OFF    (SUMS_OFF + 512*4)

#define GLOAD_LDS(g, l) __builtin_amdgcn_global_load_lds( \
    (const __attribute__((address_space(1))) void*)(g),   \
    (__attribute__((address_space(3))) void*)(l), 16, 0, 0)

__device__ __forceinline__ u16 f2bf(float v) {
    unsigned u = __builtin_bit_cast(unsigned, v);
    u += 0x7FFFu + ((u >> 16) & 1u);
    return (u16)(u >> 16);
}

// ---------- kernel 1: Gaussian tap-weight table ----------
__global__ __launch_bounds__(256) void k_wk(const float* __restrict__ coords,
                                            float* __restrict__ wkt) {
    int i = blockIdx.x * 256 + threadIdx.x;      // [b][k][l]
    if (i >= NB * NTAP * LEN) return;
    int l = i & (LEN - 1);
    int bk = i >> 14;
    int k = bk % NTAP, b = bk / NTAP;
    const float* cb = coords + (size_t)b * 3 * LEN;
    int lt = l + k * DIL - PADW;
    bool ok = (unsigned)lt < (unsigned)LEN;
    float d2 = 0.f;
#pragma unroll
    for (int j = 0; j < 3; ++j) {
        float cc = cb[j * LEN + l];
        float ct = ok ? cb[j * LEN + lt] : 0.f;
        float d = ct - cc;
        d2 += d * d;
    }
    wkt[i] = expf(-d2 * (1.f / 72.f));
}

// ---------- kernel 2: repack weights W[o][c][k] -> bf16 Wb[s][o][ck32] ----------
__global__ __launch_bounds__(256) void k_wb(const float* __restrict__ W,
                                            u16* __restrict__ Wb) {
    int i = blockIdx.x * 256 + threadIdx.x;      // 72*256*32 = 589824
    if (i >= NSTEP * 256 * 32) return;
    int j = i & 31;
    int o = (i >> 5) & 255;
    int s = i >> 13;
    int k = s >> 3;
    int c = ((s & 7) << 5) + j;
    Wb[i] = f2bf(W[((size_t)o * CIN + c) * NTAP + k]);
}

// ---------- kernel 3: transpose+convert x[b][c][l] f32 -> xTp[b][l+24][c] bf16 ----------
// padded rows [0,24) and [16408,16432) are zeros (tap boundary handling for free)
__global__ __launch_bounds__(256) void k_xt(const float* __restrict__ x,
                                            u16* __restrict__ xt) {
    __shared__ float t[64 * 65];
    const int tid = threadIdx.x;
    const int cg  = blockIdx.x;          // 0..3   (64-channel group)
    const int rg  = blockIdx.y;          // 0..256 (64-padded-row group)
    const int b   = blockIdx.z;
    const int lx0 = rg * 64 - PADW;      // x-space origin of this row group
#pragma unroll
    for (int i = 0; i < 4; ++i) {
        int c  = i * 16 + (tid >> 4);
        int l4 = (tid & 15) * 4;
        int lx = lx0 + l4;
        f32x4 v = {};
        if (lx >= 0 && lx + 3 < LEN)
            v = *reinterpret_cast<const f32x4*>(
                x + ((size_t)b * CIN + cg * 64 + c) * LEN + lx);
        float* tr = &t[c * 65 + l4];
        tr[0] = v[0]; tr[1] = v[1]; tr[2] = v[2]; tr[3] = v[3];
    }
    __syncthreads();
#pragma unroll
    for (int m = 0; m < 2; ++m) {
        int l    = m * 32 + (tid >> 3);
        int c0   = (tid & 7) * 8;
        int prow = rg * 64 + l;
        if (prow < PADROWS) {
            u16x8 o;
#pragma unroll
            for (int j = 0; j < 8; ++j) o[j] = f2bf(t[(c0 + j) * 65 + l]);
            *reinterpret_cast<u16x8*>(
                xt + ((size_t)b * PADROWS + prow) * 256 + cg * 64 + c0) = o;
        }
    }
}

// ---------- kernel 4: MFMA conv (y to d_out, BN sums via atomics) ----------
__global__ __launch_bounds__(256, 2) void k_conv(
    const u16*   __restrict__ xt,      // [8][16432][256] bf16 (padded)
    const float* __restrict__ wkt,     // [8][9][16384]
    const u16*   __restrict__ Wb,      // [72][256][32] bf16
    float* __restrict__ y,             // [8][256][16384]  (= d_out)
    float* __restrict__ sums)          // [512]
{
    const int lt = blockIdx.x;         // 128 l-tiles
    const int ob = blockIdx.y;         // 2 o-blocks
    const int b  = blockIdx.z;         // 8 batches
    const int l0 = lt * 128;
    const int tid  = threadIdx.x;
    const int lane = tid & 63;
    const int wid  = tid >> 6;
    const int wr = wid >> 1;           // wave o-half
    const int wc = wid & 1;            // wave l-half

    __shared__ u16 As[2][4096];        // [128 o][32 c], 64B rows, linear (DMA dest)
    __shared__ u16 Bs[2][4096];        // [128 l][32 c]
    __shared__ float wkl[NTAP * 128];  // tap weights for this l-tile

    for (int i = tid; i < NTAP * 128; i += 256) {
        int k = i >> 7, l = i & 127;
        wkl[i] = wkt[((size_t)b * NTAP + k) * LEN + l0 + l];
    }

    f32x4 acc_f[4][4] = {};
    f32x4 acc_t[4][4] = {};

    const u16* wbBase = Wb + (size_t)ob * 4096;
    const u16* xtBase = xt + (size_t)b * PADROWS * 256;

    auto stage = [&](int bufi, int s) {
        const int ktap  = s >> 3;
        const int cbase = (s & 7) << 5;
#pragma unroll
        for (int j = 0; j < 2; ++j) {
            const int q = wid * 2 + j;                 // wave-uniform chunk id
            const u16* ga = wbBase + (size_t)s * 8192 + q * 512 + lane * 8;
            GLOAD_LDS(ga, &As[bufi][q * 512]);
            const u16* gb = xtBase
                + (size_t)(l0 + q * 16 + (lane >> 2) + 6 * ktap) * 256
                + cbase + (lane & 3) * 8;
            GLOAD_LDS(gb, &Bs[bufi][q * 512]);
        }
    };

    stage(0, 0);
    __syncthreads();

    const int fr  = lane & 15;
    const int kc4 = (lane >> 4) * 8;   // u16 offset within 32-c row
    const int col = lane & 15;
    const int rg  = lane >> 4;

    for (int s = 0; s < NSTEP; ++s) {
        const int cur = s & 1;
        if (s < NSTEP - 1) stage(cur ^ 1, s + 1);
        bf16x8 af[4], bfv[4];
        const u16* Ab = &As[cur][(wr * 64 + fr) * 32 + kc4];
        const u16* Bb = &Bs[cur][(wc * 64 + fr) * 32 + kc4];
#pragma unroll
        for (int mi = 0; mi < 4; ++mi)
            af[mi] = *reinterpret_cast<const bf16x8*>(Ab + mi * 512);
#pragma unroll
        for (int ni = 0; ni < 4; ++ni)
            bfv[ni] = *reinterpret_cast<const bf16x8*>(Bb + ni * 512);
#pragma unroll
        for (int mi = 0; mi < 4; ++mi)
#pragma unroll
            for (int ni = 0; ni < 4; ++ni)
                acc_t[mi][ni] = __builtin_amdgcn_mfma_f32_16x16x32_bf16(
                    af[mi], bfv[ni], acc_t[mi][ni], 0, 0, 0);
        if ((s & 7) == 7) {            // tap k complete: fold Gaussian weight
            const int ktap = s >> 3;
            float wv[4];
#pragma unroll
            for (int ni = 0; ni < 4; ++ni)
                wv[ni] = wkl[ktap * 128 + wc * 64 + ni * 16 + col];
#pragma unroll
            for (int mi = 0; mi < 4; ++mi)
#pragma unroll
                for (int ni = 0; ni < 4; ++ni) {
#pragma unroll
                    for (int r = 0; r < 4; ++r)
                        acc_f[mi][ni][r] += wv[ni] * acc_t[mi][ni][r];
                    acc_t[mi][ni] = f32x4{};
                }
        }
        __syncthreads();
    }

    // epilogue: y write + per-channel sum/sqsum
    float* yb = y + ((size_t)b * COUT + ob * 128 + wr * 64) * LEN + l0 + wc * 64;
#pragma unroll
    for (int mi = 0; mi < 4; ++mi) {
#pragma unroll
        for (int r = 0; r < 4; ++r) {
            const int o_loc = mi * 16 + rg * 4 + r;
            float s1 = 0.f, s2 = 0.f;
#pragma unroll
            for (int ni = 0; ni < 4; ++ni) {
                float v = acc_f[mi][ni][r];
                yb[(size_t)o_loc * LEN + ni * 16 + col] = v;
                s1 += v;
                s2 += v * v;
            }
#pragma unroll
            for (int m = 1; m < 16; m <<= 1) {
                s1 += __shfl_xor(s1, m, 64);
                s2 += __shfl_xor(s2, m, 64);
            }
            if (col == 0) {
                int o = ob * 128 + wr * 64 + o_loc;
                atomicAdd(&sums[o], s1);
                atomicAdd(&sums[COUT + o], s2);
            }
        }
    }
}

// ---------- kernel 5: fold BN stats ----------
__global__ __launch_bounds__(256) void k_stats(const float* __restrict__ sums,
                                               const float* __restrict__ gamma,
                                               const float* __restrict__ beta,
                                               float* __restrict__ scb) {
    int o = threadIdx.x;
    const float inv_n = 1.f / (float)(NB * LEN);
    float mean = sums[o] * inv_n;
    float var  = sums[COUT + o] * inv_n - mean * mean;
    float sc = gamma[o] * rsqrtf(var + 1e-5f);
    scb[o]        = sc;
    scb[COUT + o] = beta[o] - mean * sc;
}

// ---------- kernel 6: in-place normalize + relu ----------
__global__ __launch_bounds__(256) void k_norm(float* __restrict__ y,
                                              const float* __restrict__ scb) {
    const int total4 = NB * COUT * LEN / 4;
    int i = blockIdx.x * 256 + threadIdx.x;
    for (; i < total4; i += gridDim.x * 256) {
        f32x4 v = reinterpret_cast<f32x4*>(y)[i];
        int o = (i >> 12) & 255;
        float sc = scb[o], bi = scb[COUT + o];
#pragma unroll
        for (int j = 0; j < 4; ++j)
            v[j] = fmaxf(v[j] * sc + bi, 0.f);
        reinterpret_cast<f32x4*>(y)[i] = v;
    }
}

extern "C" void kernel_launch(void* const* d_in, const int* in_sizes, int n_in,
                              void* d_out, int out_size, void* d_ws, size_t ws_size,
                              hipStream_t stream) {
    const float* x      = (const float*)d_in[0];
    const float* coords = (const float*)d_in[1];
    const float* W      = (const float*)d_in[2];
    const float* gamma  = (const float*)d_in[3];
    const float* beta   = (const float*)d_in[4];
    float* out = (float*)d_out;
    char*  ws  = (char*)d_ws;

    float* wkt  = (float*)ws;
    u16*   Wb   = (u16*)(ws + WKT_BYTES);
    u16*   xtp  = (u16*)(ws + XT_OFF);
    float* sums = (float*)(ws + SUMS_OFF);
    float* scb  = (float*)(ws + SCB_OFF);

    hipMemsetAsync(sums, 0, 512 * 4, stream);

    k_wk<<<(NB * NTAP * LEN + 255) / 256, 256, 0, stream>>>(coords, wkt);
    k_wb<<<(NSTEP * 256 * 32 + 255) / 256, 256, 0, stream>>>(W, Wb);
    k_xt<<<dim3(4, (PADROWS + 63) / 64, NB), 256, 0, stream>>>(x, xtp);

    dim3 g(LEN / 128, 2, NB);
    k_conv<<<g, 256, 0, stream>>>(xtp, wkt, Wb, out, sums);

    k_stats<<<1, 256, 0, stream>>>(sums, gamma, beta, scb);
    k_norm<<<2048, 256, 0, stream>>>(out, scb);
}

// Round 3
// 441.733 us; speedup vs baseline: 1.0290x; 1.0290x over previous
//
#include <hip/hip_runtime.h>
#include <hip/hip_bf16.h>

#define LEN   16384
#define CIN   256
#define COUT  256
#define NB    8
#define NTAP  9
#define DIL   6
#define PADW  24
#define NSTEP 72                    // 9 taps * (256/32) channel chunks
#define PADROWS (LEN + 2*PADW)      // 16432

typedef __bf16 bf16x8 __attribute__((ext_vector_type(8)));
typedef float  f32x4  __attribute__((ext_vector_type(4)));
typedef unsigned short u16;
typedef u16 u16x8 __attribute__((ext_vector_type(8)));

// ---------------- ws layout ----------------
#define WKT_BYTES  (NB*NTAP*LEN*4)             // 4,718,592
#define WB_BYTES   (NSTEP*256*32*2)            // 1,179,648
#define XT_OFF     (WKT_BYTES + WB_BYTES)
#define XT_BYTES   ((size_t)NB*PADROWS*256*2)  // 67,305,472
#define SUMS_OFF   (XT_OFF + XT_BYTES)
#define SCB_OFF    (SUMS_OFF + 512*4)

#define GLOAD_LDS(g, l) __builtin_amdgcn_global_load_lds( \
    (const __attribute__((address_space(1))) void*)(g),   \
    (__attribute__((address_space(3))) void*)(l), 16, 0, 0)

__device__ __forceinline__ u16 f2bf(float v) {
    unsigned u = __builtin_bit_cast(unsigned, v);
    u += 0x7FFFu + ((u >> 16) & 1u);
    return (u16)(u >> 16);
}

// ---------- kernel 1: Gaussian tap-weight table ----------
__global__ __launch_bounds__(256) void k_wk(const float* __restrict__ coords,
                                            float* __restrict__ wkt) {
    int i = blockIdx.x * 256 + threadIdx.x;      // [b][k][l]
    if (i >= NB * NTAP * LEN) return;
    int l = i & (LEN - 1);
    int bk = i >> 14;
    int k = bk % NTAP, b = bk / NTAP;
    const float* cb = coords + (size_t)b * 3 * LEN;
    int lt = l + k * DIL - PADW;
    bool ok = (unsigned)lt < (unsigned)LEN;
    float d2 = 0.f;
#pragma unroll
    for (int j = 0; j < 3; ++j) {
        float cc = cb[j * LEN + l];
        float ct = ok ? cb[j * LEN + lt] : 0.f;
        float d = ct - cc;
        d2 += d * d;
    }
    wkt[i] = expf(-d2 * (1.f / 72.f));
}

// ---------- kernel 2: repack weights W[o][c][k] -> bf16 Wb[s][o][ck32] ----------
__global__ __launch_bounds__(256) void k_wb(const float* __restrict__ W,
                                            u16* __restrict__ Wb) {
    int i = blockIdx.x * 256 + threadIdx.x;      // 72*256*32 = 589824
    if (i >= NSTEP * 256 * 32) return;
    int j = i & 31;
    int o = (i >> 5) & 255;
    int s = i >> 13;
    int k = s >> 3;
    int c = ((s & 7) << 5) + j;
    Wb[i] = f2bf(W[((size_t)o * CIN + c) * NTAP + k]);
}

// ---------- kernel 3: transpose+convert x[b][c][l] f32 -> xTp[b][l+24][c] bf16 ----------
__global__ __launch_bounds__(256) void k_xt(const float* __restrict__ x,
                                            u16* __restrict__ xt) {
    __shared__ float t[64 * 65];
    const int tid = threadIdx.x;
    const int cg  = blockIdx.x;          // 0..3   (64-channel group)
    const int rg  = blockIdx.y;          // 0..256 (64-padded-row group)
    const int b   = blockIdx.z;
    const int lx0 = rg * 64 - PADW;
#pragma unroll
    for (int i = 0; i < 4; ++i) {
        int c  = i * 16 + (tid >> 4);
        int l4 = (tid & 15) * 4;
        int lx = lx0 + l4;
        f32x4 v = {};
        if (lx >= 0 && lx + 3 < LEN)
            v = *reinterpret_cast<const f32x4*>(
                x + ((size_t)b * CIN + cg * 64 + c) * LEN + lx);
        float* tr = &t[c * 65 + l4];
        tr[0] = v[0]; tr[1] = v[1]; tr[2] = v[2]; tr[3] = v[3];
    }
    __syncthreads();
#pragma unroll
    for (int m = 0; m < 2; ++m) {
        int l    = m * 32 + (tid >> 3);
        int c0   = (tid & 7) * 8;
        int prow = rg * 64 + l;
        if (prow < PADROWS) {
            u16x8 o;
#pragma unroll
            for (int j = 0; j < 8; ++j) o[j] = f2bf(t[(c0 + j) * 65 + l]);
            *reinterpret_cast<u16x8*>(
                xt + ((size_t)b * PADROWS + prow) * 256 + cg * 64 + c0) = o;
        }
    }
}

// ---------- kernel 4: MFMA conv, triple-buffer + counted vmcnt + XOR swizzle ----------
__global__ __launch_bounds__(256, 2) void k_conv(
    const u16*   __restrict__ xt,      // [8][16432][256] bf16 (padded)
    const float* __restrict__ wkt,     // [8][9][16384]
    const u16*   __restrict__ Wb,      // [72][256][32] bf16
    float* __restrict__ y,             // [8][256][16384]  (= d_out)
    float* __restrict__ sums)          // [512]
{
    const int lt = blockIdx.x;         // 128 l-tiles
    const int ob = blockIdx.y;         // 2 o-blocks
    const int b  = blockIdx.z;         // 8 batches
    const int l0 = lt * 128;
    const int tid  = threadIdx.x;
    const int lane = tid & 63;
    const int wid  = tid >> 6;
    const int wr = wid >> 1;           // wave o-half
    const int wc = wid & 1;            // wave l-half

    __shared__ u16 As[3][4096];        // [128 o][32 c] 64B rows, slot-swizzled
    __shared__ u16 Bs[3][4096];        // [128 l][32 c]
    __shared__ float wkl[NTAP * 128];

    for (int i = tid; i < NTAP * 128; i += 256) {
        int k = i >> 7, l = i & 127;
        wkl[i] = wkt[((size_t)b * NTAP + k) * LEN + l0 + l];
    }

    f32x4 acc_f[4][4] = {};
    f32x4 acc_t[4][4] = {};

    const u16* wbBase = Wb + (size_t)ob * 4096;
    const u16* xtBase = xt + (size_t)b * PADROWS * 256;
    // source slot permute so that linear DMA produces the swizzled image
    const int srcswz = ((lane & 3) ^ ((lane >> 3) & 3)) * 8;   // u16 units
    const int rsub   = lane >> 2;                              // row within 16-row chunk

    auto stage = [&](int bufi, int s) {
        const int ktap  = s >> 3;
        const int cbase = (s & 7) << 5;
#pragma unroll
        for (int j = 0; j < 2; ++j) {
            const int q = wid * 2 + j;                 // wave-uniform chunk id
            const u16* ga = wbBase + (size_t)s * 8192 + (q * 16 + rsub) * 32 + srcswz;
            GLOAD_LDS(ga, &As[bufi][q * 512]);
            const u16* gb = xtBase
                + (size_t)(l0 + q * 16 + rsub + 6 * ktap) * 256
                + cbase + srcswz;
            GLOAD_LDS(gb, &Bs[bufi][q * 512]);
        }
    };

    stage(0, 0);
    stage(1, 1);
    __syncthreads();                   // prologue: full drain once

    const int fr  = lane & 15;
    // read-side swizzle: physical slot = (lane>>4) ^ ((fr>>1)&3); invariant over mi/ni
    const int rdoff = fr * 32 + (((lane >> 4) ^ ((fr >> 1) & 3)) * 8);
    const int col = lane & 15;
    const int rg  = lane >> 4;

    for (int s = 0; s < NSTEP; ++s) {
        const int cur = s % 3;
        // stage(s) complete (keep stage(s+1)'s 4 loads in flight across the barrier)
        asm volatile("s_waitcnt vmcnt(4)" ::: "memory");
        __builtin_amdgcn_s_barrier();
        if (s + 2 < NSTEP) stage((s + 2) % 3, s + 2);

        bf16x8 af[4], bfv[4];
        const u16* Ab = &As[cur][wr * 2048 + rdoff];
        const u16* Bb = &Bs[cur][wc * 2048 + rdoff];
#pragma unroll
        for (int mi = 0; mi < 4; ++mi)
            af[mi] = *reinterpret_cast<const bf16x8*>(Ab + mi * 512);
#pragma unroll
        for (int ni = 0; ni < 4; ++ni)
            bfv[ni] = *reinterpret_cast<const bf16x8*>(Bb + ni * 512);
#pragma unroll
        for (int mi = 0; mi < 4; ++mi)
#pragma unroll
            for (int ni = 0; ni < 4; ++ni)
                acc_t[mi][ni] = __builtin_amdgcn_mfma_f32_16x16x32_bf16(
                    af[mi], bfv[ni], acc_t[mi][ni], 0, 0, 0);
        if ((s & 7) == 7) {            // tap complete: fold Gaussian weight
            const int ktap = s >> 3;
            float wv[4];
#pragma unroll
            for (int ni = 0; ni < 4; ++ni)
                wv[ni] = wkl[ktap * 128 + wc * 64 + ni * 16 + col];
#pragma unroll
            for (int mi = 0; mi < 4; ++mi)
#pragma unroll
                for (int ni = 0; ni < 4; ++ni) {
#pragma unroll
                    for (int r = 0; r < 4; ++r)
                        acc_f[mi][ni][r] += wv[ni] * acc_t[mi][ni][r];
                    acc_t[mi][ni] = f32x4{};
                }
        }
    }

    // epilogue: y write + per-channel sum/sqsum
    float* yb = y + ((size_t)b * COUT + ob * 128 + wr * 64) * LEN + l0 + wc * 64;
#pragma unroll
    for (int mi = 0; mi < 4; ++mi) {
#pragma unroll
        for (int r = 0; r < 4; ++r) {
            const int o_loc = mi * 16 + rg * 4 + r;
            float s1 = 0.f, s2 = 0.f;
#pragma unroll
            for (int ni = 0; ni < 4; ++ni) {
                float v = acc_f[mi][ni][r];
                yb[(size_t)o_loc * LEN + ni * 16 + col] = v;
                s1 += v;
                s2 += v * v;
            }
#pragma unroll
            for (int m = 1; m < 16; m <<= 1) {
                s1 += __shfl_xor(s1, m, 64);
                s2 += __shfl_xor(s2, m, 64);
            }
            if (col == 0) {
                int o = ob * 128 + wr * 64 + o_loc;
                atomicAdd(&sums[o], s1);
                atomicAdd(&sums[COUT + o], s2);
            }
        }
    }
}

// ---------- kernel 5: fold BN stats ----------
__global__ __launch_bounds__(256) void k_stats(const float* __restrict__ sums,
                                               const float* __restrict__ gamma,
                                               const float* __restrict__ beta,
                                               float* __restrict__ scb) {
    int o = threadIdx.x;
    const float inv_n = 1.f / (float)(NB * LEN);
    float mean = sums[o] * inv_n;
    float var  = sums[COUT + o] * inv_n - mean * mean;
    float sc = gamma[o] * rsqrtf(var + 1e-5f);
    scb[o]        = sc;
    scb[COUT + o] = beta[o] - mean * sc;
}

// ---------- kernel 6: in-place normalize + relu ----------
__global__ __launch_bounds__(256) void k_norm(float* __restrict__ y,
                                              const float* __restrict__ scb) {
    const int total4 = NB * COUT * LEN / 4;
    int i = blockIdx.x * 256 + threadIdx.x;
    for (; i < total4; i += gridDim.x * 256) {
        f32x4 v = reinterpret_cast<f32x4*>(y)[i];
        int o = (i >> 12) & 255;
        float sc = scb[o], bi = scb[COUT + o];
#pragma unroll
        for (int j = 0; j < 4; ++j)
            v[j] = fmaxf(v[j] * sc + bi, 0.f);
        reinterpret_cast<f32x4*>(y)[i] = v;
    }
}

extern "C" void kernel_launch(void* const* d_in, const int* in_sizes, int n_in,
                              void* d_out, int out_size, void* d_ws, size_t ws_size,
                              hipStream_t stream) {
    const float* x      = (const float*)d_in[0];
    const float* coords = (const float*)d_in[1];
    const float* W      = (const float*)d_in[2];
    const float* gamma  = (const float*)d_in[3];
    const float* beta   = (const float*)d_in[4];
    float* out = (float*)d_out;
    char*  ws  = (char*)d_ws;

    float* wkt  = (float*)ws;
    u16*   Wb   = (u16*)(ws + WKT_BYTES);
    u16*   xtp  = (u16*)(ws + XT_OFF);
    float* sums = (float*)(ws + SUMS_OFF);
    float* scb  = (float*)(ws + SCB_OFF);

    hipMemsetAsync(sums, 0, 512 * 4, stream);

    k_wk<<<(NB * NTAP * LEN + 255) / 256, 256, 0, stream>>>(coords, wkt);
    k_wb<<<(NSTEP * 256 * 32 + 255) / 256, 256, 0, stream>>>(W, Wb);
    k_xt<<<dim3(4, (PADROWS + 63) / 64, NB), 256, 0, stream>>>(x, xtp);

    dim3 g(LEN / 128, 2, NB);
    k_conv<<<g, 256, 0, stream>>>(xtp, wkt, Wb, out, sums);

    k_stats<<<1, 256, 0, stream>>>(sums, gamma, beta, scb);
    k_norm<<<2048, 256, 0, stream>>>(out, scb);
}

// Round 4
// 378.265 us; speedup vs baseline: 1.2017x; 1.1678x over previous
//
#include <hip/hip_runtime.h>
#include <hip/hip_bf16.h>

#define LEN   16384
#define CIN   256
#define COUT  256
#define NB    8
#define NTAP  9
#define DIL   6
#define PADW  24
#define NSTEP 72                    // 9 taps * (256/32) channel chunks
#define PADROWS (LEN + 2*PADW)      // 16432

typedef __bf16 bf16x8 __attribute__((ext_vector_type(8)));
typedef float  f32x4  __attribute__((ext_vector_type(4)));
typedef unsigned short u16;
typedef u16 u16x8 __attribute__((ext_vector_type(8)));

// ---------------- ws layout ----------------
#define WKT_BYTES  (NB*NTAP*LEN*4)             // 4,718,592
#define WB_BYTES   (NSTEP*256*32*2)            // 1,179,648
#define XT_OFF     (WKT_BYTES + WB_BYTES)
#define XT_BYTES   ((size_t)NB*PADROWS*256*2)  // 67,305,472
#define SUMS_OFF   (XT_OFF + XT_BYTES)
#define SCB_OFF    (SUMS_OFF + 512*4)

#define GLOAD_LDS(g, l) __builtin_amdgcn_global_load_lds( \
    (const __attribute__((address_space(1))) void*)(g),   \
    (__attribute__((address_space(3))) void*)(l), 16, 0, 0)

__device__ __forceinline__ u16 f2bf(float v) {
    unsigned u = __builtin_bit_cast(unsigned, v);
    u += 0x7FFFu + ((u >> 16) & 1u);
    return (u16)(u >> 16);
}

// ---------- kernel 1: Gaussian tap-weight table ----------
__global__ __launch_bounds__(256) void k_wk(const float* __restrict__ coords,
                                            float* __restrict__ wkt) {
    int i = blockIdx.x * 256 + threadIdx.x;      // [b][k][l]
    if (i >= NB * NTAP * LEN) return;
    int l = i & (LEN - 1);
    int bk = i >> 14;
    int k = bk % NTAP, b = bk / NTAP;
    const float* cb = coords + (size_t)b * 3 * LEN;
    int lt = l + k * DIL - PADW;
    bool ok = (unsigned)lt < (unsigned)LEN;
    float d2 = 0.f;
#pragma unroll
    for (int j = 0; j < 3; ++j) {
        float cc = cb[j * LEN + l];
        float ct = ok ? cb[j * LEN + lt] : 0.f;
        float d = ct - cc;
        d2 += d * d;
    }
    wkt[i] = expf(-d2 * (1.f / 72.f));
}

// ---------- kernel 2: repack weights W[o][c][k] -> bf16 Wb[s][o][ck32] ----------
__global__ __launch_bounds__(256) void k_wb(const float* __restrict__ W,
                                            u16* __restrict__ Wb) {
    int i = blockIdx.x * 256 + threadIdx.x;      // 72*256*32 = 589824
    if (i >= NSTEP * 256 * 32) return;
    int j = i & 31;
    int o = (i >> 5) & 255;
    int s = i >> 13;
    int k = s >> 3;
    int c = ((s & 7) << 5) + j;
    Wb[i] = f2bf(W[((size_t)o * CIN + c) * NTAP + k]);
}

// ---------- kernel 3: transpose+convert x[b][c][l] f32 -> xTp[b][l+24][c] bf16 ----------
__global__ __launch_bounds__(256) void k_xt(const float* __restrict__ x,
                                            u16* __restrict__ xt) {
    __shared__ float t[64 * 65];
    const int tid = threadIdx.x;
    const int cg  = blockIdx.x;          // 0..3   (64-channel group)
    const int rg  = blockIdx.y;          // 0..256 (64-padded-row group)
    const int b   = blockIdx.z;
    const int lx0 = rg * 64 - PADW;
#pragma unroll
    for (int i = 0; i < 4; ++i) {
        int c  = i * 16 + (tid >> 4);
        int l4 = (tid & 15) * 4;
        int lx = lx0 + l4;
        f32x4 v = {};
        if (lx >= 0 && lx + 3 < LEN)
            v = *reinterpret_cast<const f32x4*>(
                x + ((size_t)b * CIN + cg * 64 + c) * LEN + lx);
        float* tr = &t[c * 65 + l4];
        tr[0] = v[0]; tr[1] = v[1]; tr[2] = v[2]; tr[3] = v[3];
    }
    __syncthreads();
#pragma unroll
    for (int m = 0; m < 2; ++m) {
        int l    = m * 32 + (tid >> 3);
        int c0   = (tid & 7) * 8;
        int prow = rg * 64 + l;
        if (prow < PADROWS) {
            u16x8 o;
#pragma unroll
            for (int j = 0; j < 8; ++j) o[j] = f2bf(t[(c0 + j) * 65 + l]);
            *reinterpret_cast<u16x8*>(
                xt + ((size_t)b * PADROWS + prow) * 256 + cg * 64 + c0) = o;
        }
    }
}

// ---------- kernel 4: MFMA conv — m201-style 2-barrier phases, frag read-ahead ----------
__global__ __launch_bounds__(256, 2) void k_conv(
    const u16*   __restrict__ xt,      // [8][16432][256] bf16 (padded)
    const float* __restrict__ wkt,     // [8][9][16384]
    const u16*   __restrict__ Wb,      // [72][256][32] bf16
    float* __restrict__ y,             // [8][256][16384]  (= d_out)
    float* __restrict__ sums)          // [512]
{
    const int lt = blockIdx.x;         // 128 l-tiles
    const int ob = blockIdx.y;         // 2 o-blocks
    const int b  = blockIdx.z;         // 8 batches
    const int l0 = lt * 128;
    const int tid  = threadIdx.x;
    const int lane = tid & 63;
    const int wid  = tid >> 6;
    const int wr = wid >> 1;           // wave o-half
    const int wc = wid & 1;            // wave l-half

    __shared__ u16 As[4][4096];        // 4 slots, [128 o][32 c] 64B rows, slot-swizzled
    __shared__ u16 Bs[4][4096];
    __shared__ float wkl[NTAP * 128];

    for (int i = tid; i < NTAP * 128; i += 256) {
        int k = i >> 7, l = i & 127;
        wkl[i] = wkt[((size_t)b * NTAP + k) * LEN + l0 + l];
    }

    f32x4 acc_f[4][4] = {};
    f32x4 acc_t[4][4] = {};

    const u16* wbBase = Wb + (size_t)ob * 4096;
    const u16* xtBase = xt + (size_t)b * PADROWS * 256;
    const int srcswz = ((lane & 3) ^ ((lane >> 3) & 3)) * 8;   // u16 units
    const int rsub   = lane >> 2;

    auto stage = [&](int s) {
        const int bufi  = s & 3;
        const int ktap  = s >> 3;
        const int cbase = (s & 7) << 5;
#pragma unroll
        for (int j = 0; j < 2; ++j) {
            const int q = wid * 2 + j;
            const u16* ga = wbBase + (size_t)s * 8192 + (q * 16 + rsub) * 32 + srcswz;
            GLOAD_LDS(ga, &As[bufi][q * 512]);
            const u16* gb = xtBase
                + (size_t)(l0 + q * 16 + rsub + 6 * ktap) * 256
                + cbase + srcswz;
            GLOAD_LDS(gb, &Bs[bufi][q * 512]);
        }
    };

    const int fr    = lane & 15;
    const int rdoff = fr * 32 + (((lane >> 4) ^ ((fr >> 1) & 3)) * 8);
    const int col   = lane & 15;
    const int rg    = lane >> 4;

    auto readf = [&](bf16x8* af, bf16x8* bfv, int s) {
        const u16* Ab = &As[s & 3][wr * 2048 + rdoff];
        const u16* Bb = &Bs[s & 3][wc * 2048 + rdoff];
#pragma unroll
        for (int mi = 0; mi < 4; ++mi)
            af[mi] = *reinterpret_cast<const bf16x8*>(Ab + mi * 512);
#pragma unroll
        for (int ni = 0; ni < 4; ++ni)
            bfv[ni] = *reinterpret_cast<const bf16x8*>(Bb + ni * 512);
    };

    auto domfma = [&](bf16x8* af, bf16x8* bfv) {
        __builtin_amdgcn_s_setprio(1);
#pragma unroll
        for (int mi = 0; mi < 4; ++mi)
#pragma unroll
            for (int ni = 0; ni < 4; ++ni)
                acc_t[mi][ni] = __builtin_amdgcn_mfma_f32_16x16x32_bf16(
                    af[mi], bfv[ni], acc_t[mi][ni], 0, 0, 0);
        __builtin_amdgcn_s_setprio(0);
    };

    auto fold = [&](int s) {
        const int ktap = s >> 3;
        float wv[4];
#pragma unroll
        for (int ni = 0; ni < 4; ++ni)
            wv[ni] = wkl[ktap * 128 + wc * 64 + ni * 16 + col];
#pragma unroll
        for (int mi = 0; mi < 4; ++mi)
#pragma unroll
            for (int ni = 0; ni < 4; ++ni) {
#pragma unroll
                for (int r = 0; r < 4; ++r)
                    acc_f[mi][ni][r] += wv[ni] * acc_t[mi][ni][r];
                acc_t[mi][ni] = f32x4{};
            }
    };

    bf16x8 afA[4], bfA[4], afB[4], bfB[4];

    // prologue: 3 stages in flight, wait until 0,1 landed, read step-0 frags
    stage(0); stage(1); stage(2);
    asm volatile("s_waitcnt vmcnt(4)" ::: "memory");
    __builtin_amdgcn_s_barrier();
    readf(afA, bfA, 0);

    // 36 double-step iterations; 2 barriers per half (m201 rhythm)
    for (int t = 0; t < 36; ++t) {
        const int s0 = 2 * t;
        const int s1 = 2 * t + 1;
        // ---- half 0: compute s0 (bank A); read s0+1 into bank B ----
        readf(afB, bfB, s0 + 1);                 // s0+1 <= 71 always
        if (t <= 34) stage(s0 + 3);              // stage 3..71 (odd)
        if (t < 35) asm volatile("s_waitcnt vmcnt(4)" ::: "memory");
        __builtin_amdgcn_s_barrier();
        domfma(afA, bfA);
        __builtin_amdgcn_s_barrier();
        // ---- half 1: compute s1 (bank B); read s1+1 into bank A ----
        if (t < 35) readf(afA, bfA, s1 + 1);
        if (t <= 33) stage(s1 + 3);              // stage 4..70 (even)
        if (t < 34) asm volatile("s_waitcnt vmcnt(4)" ::: "memory");
        else if (t == 34) asm volatile("s_waitcnt vmcnt(0)" ::: "memory");
        __builtin_amdgcn_s_barrier();
        domfma(afB, bfB);
        if ((t & 3) == 3) fold(s1);              // s1&7==7: tap complete
        __builtin_amdgcn_s_barrier();
    }

    // epilogue: y write + per-channel sum/sqsum
    float* yb = y + ((size_t)b * COUT + ob * 128 + wr * 64) * LEN + l0 + wc * 64;
#pragma unroll
    for (int mi = 0; mi < 4; ++mi) {
#pragma unroll
        for (int r = 0; r < 4; ++r) {
            const int o_loc = mi * 16 + rg * 4 + r;
            float s1 = 0.f, s2 = 0.f;
#pragma unroll
            for (int ni = 0; ni < 4; ++ni) {
                float v = acc_f[mi][ni][r];
                yb[(size_t)o_loc * LEN + ni * 16 + col] = v;
                s1 += v;
                s2 += v * v;
            }
#pragma unroll
            for (int m = 1; m < 16; m <<= 1) {
                s1 += __shfl_xor(s1, m, 64);
                s2 += __shfl_xor(s2, m, 64);
            }
            if (col == 0) {
                int o = ob * 128 + wr * 64 + o_loc;
                atomicAdd(&sums[o], s1);
                atomicAdd(&sums[COUT + o], s2);
            }
        }
    }
}

// ---------- kernel 5: fold BN stats ----------
__global__ __launch_bounds__(256) void k_stats(const float* __restrict__ sums,
                                               const float* __restrict__ gamma,
                                               const float* __restrict__ beta,
                                               float* __restrict__ scb) {
    int o = threadIdx.x;
    const float inv_n = 1.f / (float)(NB * LEN);
    float mean = sums[o] * inv_n;
    float var  = sums[COUT + o] * inv_n - mean * mean;
    float sc = gamma[o] * rsqrtf(var + 1e-5f);
    scb[o]        = sc;
    scb[COUT + o] = beta[o] - mean * sc;
}

// ---------- kernel 6: in-place normalize + relu ----------
__global__ __launch_bounds__(256) void k_norm(float* __restrict__ y,
                                              const float* __restrict__ scb) {
    const int total4 = NB * COUT * LEN / 4;
    int i = blockIdx.x * 256 + threadIdx.x;
    for (; i < total4; i += gridDim.x * 256) {
        f32x4 v = reinterpret_cast<f32x4*>(y)[i];
        int o = (i >> 12) & 255;
        float sc = scb[o], bi = scb[COUT + o];
#pragma unroll
        for (int j = 0; j < 4; ++j)
            v[j] = fmaxf(v[j] * sc + bi, 0.f);
        reinterpret_cast<f32x4*>(y)[i] = v;
    }
}

extern "C" void kernel_launch(void* const* d_in, const int* in_sizes, int n_in,
                              void* d_out, int out_size, void* d_ws, size_t ws_size,
                              hipStream_t stream) {
    const float* x      = (const float*)d_in[0];
    const float* coords = (const float*)d_in[1];
    const float* W      = (const float*)d_in[2];
    const float* gamma  = (const float*)d_in[3];
    const float* beta   = (const float*)d_in[4];
    float* out = (float*)d_out;
    char*  ws  = (char*)d_ws;

    float* wkt  = (float*)ws;
    u16*   Wb   = (u16*)(ws + WKT_BYTES);
    u16*   xtp  = (u16*)(ws + XT_OFF);
    float* sums = (float*)(ws + SUMS_OFF);
    float* scb  = (float*)(ws + SCB_OFF);

    hipMemsetAsync(sums, 0, 512 * 4, stream);

    k_wk<<<(NB * NTAP * LEN + 255) / 256, 256, 0, stream>>>(coords, wkt);
    k_wb<<<(NSTEP * 256 * 32 + 255) / 256, 256, 0, stream>>>(W, Wb);
    k_xt<<<dim3(4, (PADROWS + 63) / 64, NB), 256, 0, stream>>>(x, xtp);

    dim3 g(LEN / 128, 2, NB);
    k_conv<<<g, 256, 0, stream>>>(xtp, wkt, Wb, out, sums);

    k_stats<<<1, 256, 0, stream>>>(sums, gamma, beta, scb);
    k_norm<<<2048, 256, 0, stream>>>(out, scb);
}